// Round 6
// baseline (135.910 us; speedup 1.0000x reference)
//
#include <hip/hip_runtime.h>

// Problem constants (fixed by the reference module)
#define B_ 16
#define L_ 2048
#define D_ 128
#define GROUP_ 16
#define NG_ (L_ / GROUP_)   // 128
#define LOG2E_ 1.44269504088896340736f

typedef float v2 __attribute__((ext_vector_type(2)));

// DPP-based butterfly add within each 16-lane row (full-rate VALU, no LDS).
template<int CTRL>
__device__ __forceinline__ float dpp_add(float v) {
    int x = __builtin_amdgcn_update_dpp(0, __float_as_int(v), CTRL, 0xF, 0xF, false);
    return v + __int_as_float(x);
}
__device__ __forceinline__ float row16_sum(float v) {
    v = dpp_add<0xB1>(v);   // quad_perm(1,0,3,2)  ~ xor 1
    v = dpp_add<0x4E>(v);   // quad_perm(2,3,0,1)  ~ xor 2
    v = dpp_add<0x141>(v);  // row_half_mirror     ~ xor 4
    v = dpp_add<0x140>(v);  // row_mirror          ~ xor 8
    return v;
}

// lgkm-only barrier: orders LDS producer/consumer + WAR across the step
// WITHOUT draining vmcnt (plain __syncthreads emits s_waitcnt vmcnt(0)
// lgkmcnt(0), serializing any in-flight global traffic on the 16-step
// critical path). Single asm block so no memory op can slip between the
// wait and the barrier.
#define LGKM_BARRIER() asm volatile("s_waitcnt lgkmcnt(0)\n\ts_barrier" ::: "memory")

// R15: R14 math (proven: kernel fell below the 43us memsets) + two fixes
// aimed at the wall-minus-busy gap:
//  (a) Evidence: VGPR_Count=44 vs >=80 declared loop-invariant floats in
//      every 256t round -> compiler sinks constant loads + derived-const
//      recompute into the j-loop. Fix: stage the 6 DERIVED const arrays in
//      LDS once per block; loop reads them via ds_read_b128 (cheap lgkm,
//      no recompute, no global reloads). Live reg set becomes structurally
//      small -> nothing to demote.
//  (b) In-loop __syncthreads -> LGKM_BARRIER (no vmcnt drain per step).
// STEP_LOOP macro: SELFN = min (S<0) or max (S>=0), uniform per launch.
#define STEP_LOOP(SELFN)                                                      \
    for (int j = 0; j < GROUP_; ++j) {                                        \
        const int p = j & 1;                                                  \
        v2 xjv[4], Wi[4], Wj[4];                                              \
        {                                                                     \
            float4 tA = *(const float4*)&s_xj[p][d0];                         \
            float4 tB = *(const float4*)&s_xj[p][d0 + 4];                     \
            xjv[0] = (v2){tA.x, tA.y}; xjv[1] = (v2){tA.z, tA.w};             \
            xjv[2] = (v2){tB.x, tB.y}; xjv[3] = (v2){tB.z, tB.w};             \
            float4 wA = *(const float4*)(cbase + 0 * D_ + d0);                \
            float4 wB = *(const float4*)(cbase + 0 * D_ + d0 + 4);            \
            float4 vA = *(const float4*)(cbase + 1 * D_ + d0);                \
            float4 vB = *(const float4*)(cbase + 1 * D_ + d0 + 4);            \
            Wi[0] = (v2){wA.x, wA.y}; Wi[1] = (v2){wA.z, wA.w};               \
            Wi[2] = (v2){wB.x, wB.y}; Wi[3] = (v2){wB.z, wB.w};               \
            Wj[0] = (v2){vA.x, vA.y}; Wj[1] = (v2){vA.z, vA.w};               \
            Wj[2] = (v2){vB.x, vB.y}; Wj[3] = (v2){vB.z, vB.w};               \
        }                                                                     \
        v2 sv = (v2){0.0f, 0.0f};                                             \
        _Pragma("unroll")                                                     \
        for (int k = 0; k < 4; ++k) sv = __builtin_elementwise_fma(cxi[k], Wi[k], sv); \
        _Pragma("unroll")                                                     \
        for (int k = 0; k < 4; ++k) sv = __builtin_elementwise_fma(xjv[k], Wj[k], sv); \
        const float sim = row16_sum(sv.x + sv.y);                             \
        const v2 simv = (v2){sim, sim};                                       \
        v2 G1S[4], B1S[4], G2c[4], B2c[4];                                    \
        {                                                                     \
            float4 aA = *(const float4*)(cbase + 2 * D_ + d0);                \
            float4 aB = *(const float4*)(cbase + 2 * D_ + d0 + 4);            \
            float4 bA = *(const float4*)(cbase + 3 * D_ + d0);                \
            float4 bB = *(const float4*)(cbase + 3 * D_ + d0 + 4);            \
            float4 cA = *(const float4*)(cbase + 4 * D_ + d0);                \
            float4 cB = *(const float4*)(cbase + 4 * D_ + d0 + 4);            \
            float4 dA = *(const float4*)(cbase + 5 * D_ + d0);                \
            float4 dB = *(const float4*)(cbase + 5 * D_ + d0 + 4);            \
            G1S[0] = (v2){aA.x, aA.y}; G1S[1] = (v2){aA.z, aA.w};             \
            G1S[2] = (v2){aB.x, aB.y}; G1S[3] = (v2){aB.z, aB.w};             \
            B1S[0] = (v2){bA.x, bA.y}; B1S[1] = (v2){bA.z, bA.w};             \
            B1S[2] = (v2){bB.x, bB.y}; B1S[3] = (v2){bB.z, bB.w};             \
            G2c[0] = (v2){cA.x, cA.y}; G2c[1] = (v2){cA.z, cA.w};             \
            G2c[2] = (v2){cB.x, cB.y}; G2c[3] = (v2){cB.z, cB.w};             \
            B2c[0] = (v2){dA.x, dA.y}; B2c[1] = (v2){dA.z, dA.w};             \
            B2c[2] = (v2){dB.x, dB.y}; B2c[3] = (v2){dB.z, dB.w};             \
        }                                                                     \
        _Pragma("unroll")                                                     \
        for (int k = 0; k < 4; ++k) {                                         \
            v2 u  = __builtin_elementwise_fma(simv, xjv[k], cxi[k]);          \
            v2 e1 = (v2){__builtin_amdgcn_exp2f(u.x), __builtin_amdgcn_exp2f(u.y)}; \
            v2 d1 = e1 + onev;                                                \
            v2 r1 = (v2){__builtin_amdgcn_rcpf(d1.x), __builtin_amdgcn_rcpf(d1.y)}; \
            v2 tnS = __builtin_elementwise_fma(G1S[k], r1, B1S[k]);           \
            v2 FvS = SELFN(tnS, tnS * leak);                                  \
            za[k] += FvS;                                                     \
            v2 e2 = (v2){__builtin_amdgcn_exp2f(za[k].x), __builtin_amdgcn_exp2f(za[k].y)}; \
            v2 d2 = e2 + onev;                                                \
            v2 r2 = (v2){__builtin_amdgcn_rcpf(d2.x), __builtin_amdgcn_rcpf(d2.y)}; \
            cxi[k] = __builtin_elementwise_fma(G2c[k], r2, cxi[k] + B2c[k]);  \
        }                                                                     \
        if (j + 1 < GROUP_ && row == j + 1) {                                 \
            float4 oA = {cxi[0].x, cxi[0].y, cxi[1].x, cxi[1].y};             \
            float4 oB = {cxi[2].x, cxi[2].y, cxi[3].x, cxi[3].y};             \
            *(float4*)&s_xj[p ^ 1][d0]     = oA;                              \
            *(float4*)&s_xj[p ^ 1][d0 + 4] = oB;                              \
        }                                                                     \
        LGKM_BARRIER();                                                       \
    }

__global__ __launch_bounds__(256, 6) void ncn_kernel(
    const float* __restrict__ x,       // (B, L, D)
    const int*   __restrict__ gt,      // (B, L) permutation
    const int*   __restrict__ ctxlens, // (B,)
    const float* __restrict__ W,       // (2D,)
    const float* __restrict__ nalpha,  // (2,)
    const float* __restrict__ ngamma,  // (2D,)
    const float* __restrict__ nbeta,   // (2D,)
    float* __restrict__ out)           // (2, B, L, D) concat: yi_out, ya_out
{
    const int blk = blockIdx.x;
    const int b   = blk >> 7;      // / NG_
    const int g   = blk & (NG_ - 1);
    const int tid = threadIdx.x;
    const int row = tid >> 4;      // 0..15 (token within group)
    const int rl  = tid & 15;      // 0..15 (lane within row)
    const int d0  = rl << 3;       // 8 d-elements per thread

    __shared__ float s_xj[2][D_];  // double-buffered broadcast row (holds cxj)
    __shared__ float s_c[6][D_];   // derived consts: Wi', Wj', G1S, B1S, G2c, B2c

    const float a1 = nalpha[0];
    const float a2 = nalpha[1];
    const float ca = -a1 * LOG2E_;        // u = ca*(xi + sim*xj); ALPHA=0.5 folded
    const float S  = -2.0f * a2 * LOG2E_; // za = S*xa, so exp2(za) direct
    const float inv_ca = 1.0f / ca;
    const bool  selMin = (S < 0.0f);      // leaky-relu under sign flip

    // Cooperative derived-const staging (once per block; dims 0..127).
    if (tid < D_) {
        const int d = tid;
        float w  = W[d],          wj = W[D_ + d];
        float g1 = ngamma[d],     g2 = ngamma[D_ + d];
        float b1 = nbeta[d],      b2 = nbeta[D_ + d];
        s_c[0][d] = w  * inv_ca;          // Wi' (pre-scaled: sim from cxi)
        s_c[1][d] = wj * inv_ca;          // Wj'
        s_c[2][d] = (S * 2.0f) * g1;      // G1S
        s_c[3][d] = S * (b1 - g1);        // B1S
        s_c[4][d] = (ca * 2.0f) * g2;     // G2c
        s_c[5][d] = ca * (b2 - g2);       // B2c
    }

    // Gather this row's token; state is cxi = ca * xi.
    const int l   = g * GROUP_ + row;
    const int tok = gt[b * L_ + l];
    const float* xp = x + ((size_t)(b * L_ + tok)) * D_ + d0;

    v2 cxi[4], za[4];
    {
        float4 xA = *(const float4*)xp;
        float4 xB = *(const float4*)(xp + 4);
        const v2 cav = (v2){ca, ca};
        cxi[0] = cav * (v2){xA.x, xA.y}; cxi[1] = cav * (v2){xA.z, xA.w};
        cxi[2] = cav * (v2){xB.x, xB.y}; cxi[3] = cav * (v2){xB.z, xB.w};
    }
#pragma unroll
    for (int k = 0; k < 4; ++k) za[k] = (v2){0.0f, 0.0f};

    // Row 0 publishes its initial cxi into buffer 0
    if (row == 0) {
        float4 oA = {cxi[0].x, cxi[0].y, cxi[1].x, cxi[1].y};
        float4 oB = {cxi[2].x, cxi[2].y, cxi[3].x, cxi[3].y};
        *(float4*)&s_xj[0][d0]     = oA;
        *(float4*)&s_xj[0][d0 + 4] = oB;
    }
    __syncthreads();   // one-time full barrier (consts + initial publish)

    // Opaque const base: belt-and-suspenders against LICM of the in-loop
    // const reads (the memory-clobber barrier already blocks hoisting).
    const float* cbase = &s_c[0][0];
    asm volatile("" : "+v"(cbase));

    const v2 onev = (v2){1.0f, 1.0f};
    const v2 leak = (v2){0.01f, 0.01f};

    // Uniform split: each path pays exactly one v_pk_min / v_pk_max per elem.
    if (selMin) {
        STEP_LOOP(__builtin_elementwise_min)
    } else {
        STEP_LOOP(__builtin_elementwise_max)
    }

    // Recover xi = cxi / ca and xa = za / S.
    const float invS = 1.0f / S;
    const v2 invSv  = (v2){invS, invS};
    const v2 invCav = (v2){inv_ca, inv_ca};
    v2 xi[4], xa[4];
#pragma unroll
    for (int k = 0; k < 4; ++k) {
        xi[k] = cxi[k] * invCav;
        xa[k] = za[k] * invSv;
    }

    const bool valid = (g * GROUP_) < ctxlens[b];
    if (!valid) {
#pragma unroll
        for (int k = 0; k < 4; ++k) { xi[k] = (v2){0,0}; xa[k] = (v2){0,0}; }
    }

    // Scatter back through the permutation (bijective -> every out elem written)
    float* o1 = out + ((size_t)(b * L_ + tok)) * D_ + d0;
    float* o2 = o1 + (size_t)B_ * L_ * D_;
    float4 s1A = {xi[0].x, xi[0].y, xi[1].x, xi[1].y};
    float4 s1B = {xi[2].x, xi[2].y, xi[3].x, xi[3].y};
    float4 s2A = {xa[0].x, xa[0].y, xa[1].x, xa[1].y};
    float4 s2B = {xa[2].x, xa[2].y, xa[3].x, xa[3].y};
    *(float4*)o1       = s1A;
    *(float4*)(o1 + 4) = s1B;
    *(float4*)o2       = s2A;
    *(float4*)(o2 + 4) = s2B;
}

extern "C" void kernel_launch(void* const* d_in, const int* in_sizes, int n_in,
                              void* d_out, int out_size, void* d_ws, size_t ws_size,
                              hipStream_t stream) {
    const float* x  = (const float*)d_in[0];
    const int*   gt = (const int*)d_in[1];
    const int*   cl = (const int*)d_in[2];
    const float* W  = (const float*)d_in[3];
    const float* na = (const float*)d_in[4];
    const float* ng = (const float*)d_in[5];
    const float* nb = (const float*)d_in[6];
    float* out = (float*)d_out;

    ncn_kernel<<<B_ * NG_, 256, 0, stream>>>(x, gt, cl, W, na, ng, nb, out);
}

// Round 7
// 111.437 us; speedup vs baseline: 1.2196x; 1.2196x over previous
//
#include <hip/hip_runtime.h>

// Problem constants (fixed by the reference module)
#define B_ 16
#define L_ 2048
#define D_ 128
#define GROUP_ 16
#define NG_ (L_ / GROUP_)   // 128
#define LOG2E_ 1.44269504088896340736f

typedef float v2 __attribute__((ext_vector_type(2)));

// DPP-based butterfly add within each 16-lane row (full-rate VALU, no LDS).
template<int CTRL>
__device__ __forceinline__ float dpp_add(float v) {
    int x = __builtin_amdgcn_update_dpp(0, __float_as_int(v), CTRL, 0xF, 0xF, false);
    return v + __int_as_float(x);
}
__device__ __forceinline__ float row16_sum(float v) {
    v = dpp_add<0xB1>(v);   // quad_perm(1,0,3,2)  ~ xor 1
    v = dpp_add<0x4E>(v);   // quad_perm(2,3,0,1)  ~ xor 2
    v = dpp_add<0x141>(v);  // row_half_mirror     ~ xor 4
    v = dpp_add<0x140>(v);  // row_mirror          ~ xor 8
    return v;
}

// lgkm-only barrier: orders the LDS double-buffer handoff WITHOUT the
// vmcnt(0) drain that __syncthreads emits (any straggler global reads
// would serialize on the 16-step critical path). All loop traffic that
// needs ordering is LDS (lgkm).
#define LGKM_BARRIER() asm volatile("s_waitcnt lgkmcnt(0)\n\ts_barrier" ::: "memory")

// R16 = R14 (best measured, ~40us kernel) + allocator fix.
// Evidence trail: every round reports VGPR_Count (44/28/60/40) far below
// the declared live set; R13 showed this demotion is AGPR shuffling (no
// scratch traffic, yet +25% issue); R15's LDS-const fix regressed (4-way
// bank conflicts on the lgkm critical path + launch_bounds(256,6) caused
// real scratch spills: WRITE_SIZE 32768->48510 KB).
// Fix here: amdgpu_waves_per_eu(4,4) pins the compiler's occupancy TARGET
// to our actual runtime occupancy (4 blocks/CU x 4 waves = 4 waves/SIMD,
// 128-VGPR budget) so it has no reason to demote the ~30 loop-invariant
// constants to AGPRs. Diagnostic tell: VGPR_Count should jump to 80-128.
// Also: in-loop barrier is lgkm-only (no per-step vmcnt drain).
//
// STEP_LOOP macro: SELFN = min (S<0) or max (S>=0), uniform per launch.
#define STEP_LOOP(SELFN)                                                      \
    for (int j = 0; j < GROUP_; ++j) {                                        \
        const int p = j & 1;                                                  \
        v2 xjv[4];                                                            \
        {                                                                     \
            float4 tA = *(const float4*)&s_xj[p][d0];                         \
            float4 tB = *(const float4*)&s_xj[p][d0 + 4];                     \
            xjv[0] = (v2){tA.x, tA.y}; xjv[1] = (v2){tA.z, tA.w};             \
            xjv[2] = (v2){tB.x, tB.y}; xjv[3] = (v2){tB.z, tB.w};             \
        }                                                                     \
        v2 sv = (v2){0.0f, 0.0f};                                             \
        _Pragma("unroll")                                                     \
        for (int k = 0; k < 4; ++k) sv = __builtin_elementwise_fma(cxi[k], Wi[k], sv); \
        _Pragma("unroll")                                                     \
        for (int k = 0; k < 4; ++k) sv = __builtin_elementwise_fma(xjv[k], Wj[k], sv); \
        const float sim = row16_sum(sv.x + sv.y);                             \
        const v2 simv = (v2){sim, sim};                                       \
        _Pragma("unroll")                                                     \
        for (int k = 0; k < 4; ++k) {                                         \
            v2 u  = __builtin_elementwise_fma(simv, xjv[k], cxi[k]);          \
            v2 r1 = (v2){__builtin_amdgcn_rcpf(__builtin_amdgcn_exp2f(u.x) + 1.0f),   \
                         __builtin_amdgcn_rcpf(__builtin_amdgcn_exp2f(u.y) + 1.0f)};  \
            v2 tnS = __builtin_elementwise_fma(G1S[k], r1, B1S[k]);           \
            v2 FvS = SELFN(tnS, tnS * leak);                                  \
            za[k] += FvS;                                                     \
            v2 r2 = (v2){__builtin_amdgcn_rcpf(__builtin_amdgcn_exp2f(za[k].x) + 1.0f), \
                         __builtin_amdgcn_rcpf(__builtin_amdgcn_exp2f(za[k].y) + 1.0f)}; \
            cxi[k] = __builtin_elementwise_fma(G2c[k], r2, cxi[k] + B2c[k]);  \
        }                                                                     \
        if (j + 1 < GROUP_ && row == j + 1) {                                 \
            float4 oA = {cxi[0].x, cxi[0].y, cxi[1].x, cxi[1].y};             \
            float4 oB = {cxi[2].x, cxi[2].y, cxi[3].x, cxi[3].y};             \
            *(float4*)&s_xj[p ^ 1][d0]     = oA;                              \
            *(float4*)&s_xj[p ^ 1][d0 + 4] = oB;                              \
        }                                                                     \
        LGKM_BARRIER();                                                       \
    }

__global__ __launch_bounds__(256)
__attribute__((amdgpu_waves_per_eu(4, 4)))
void ncn_kernel(
    const float* __restrict__ x,       // (B, L, D)
    const int*   __restrict__ gt,      // (B, L) permutation
    const int*   __restrict__ ctxlens, // (B,)
    const float* __restrict__ W,       // (2D,)
    const float* __restrict__ nalpha,  // (2,)
    const float* __restrict__ ngamma,  // (2D,)
    const float* __restrict__ nbeta,   // (2D,)
    float* __restrict__ out)           // (2, B, L, D) concat: yi_out, ya_out
{
    const int blk = blockIdx.x;
    const int b   = blk >> 7;      // / NG_
    const int g   = blk & (NG_ - 1);
    const int tid = threadIdx.x;
    const int row = tid >> 4;      // 0..15 (token within group)
    const int rl  = tid & 15;      // 0..15 (lane within row)
    const int d0  = rl << 3;       // 8 d-elements per thread

    __shared__ float s_xj[2][D_];  // double-buffered broadcast row (holds cxj)

    const float a1 = nalpha[0];
    const float a2 = nalpha[1];
    const float ca = -a1 * LOG2E_;        // u = ca*(xi + sim*xj); ALPHA=0.5 folded
    const float S  = -2.0f * a2 * LOG2E_; // za = S*xa, so exp2(za) direct
    const float inv_ca = 1.0f / ca;       // (a1 != 0 on this problem's inputs)
    const bool  selMin = (S < 0.0f);      // leaky-relu under sign flip

    // Per-chunk constants in registers (reused 16x), as packed v2 pairs.
    // Wi,Wj pre-scaled by 1/ca so sim = dot(cxi,Wi') + dot(cxj,Wj').
    // G2c,B2c pre-scaled by ca so cxi' = fma(G2c, r2, cxi + B2c).
    v2 Wi[4], Wj[4], G1S[4], B1S[4], G2c[4], B2c[4];
    {
        float4 wA = *(const float4*)(W + d0);
        float4 wB = *(const float4*)(W + d0 + 4);
        float4 vA = *(const float4*)(W + D_ + d0);
        float4 vB = *(const float4*)(W + D_ + d0 + 4);
        Wi[0] = inv_ca * (v2){wA.x, wA.y}; Wi[1] = inv_ca * (v2){wA.z, wA.w};
        Wi[2] = inv_ca * (v2){wB.x, wB.y}; Wi[3] = inv_ca * (v2){wB.z, wB.w};
        Wj[0] = inv_ca * (v2){vA.x, vA.y}; Wj[1] = inv_ca * (v2){vA.z, vA.w};
        Wj[2] = inv_ca * (v2){vB.x, vB.y}; Wj[3] = inv_ca * (v2){vB.z, vB.w};

        float4 g1A = *(const float4*)(ngamma + d0);
        float4 g1B = *(const float4*)(ngamma + d0 + 4);
        float4 g2A = *(const float4*)(ngamma + D_ + d0);
        float4 g2B = *(const float4*)(ngamma + D_ + d0 + 4);
        float4 b1A = *(const float4*)(nbeta + d0);
        float4 b1B = *(const float4*)(nbeta + d0 + 4);
        float4 b2A = *(const float4*)(nbeta + D_ + d0);
        float4 b2B = *(const float4*)(nbeta + D_ + d0 + 4);

        v2 g1v[4] = {(v2){g1A.x,g1A.y},(v2){g1A.z,g1A.w},(v2){g1B.x,g1B.y},(v2){g1B.z,g1B.w}};
        v2 b1v[4] = {(v2){b1A.x,b1A.y},(v2){b1A.z,b1A.w},(v2){b1B.x,b1B.y},(v2){b1B.z,b1B.w}};
        v2 g2v[4] = {(v2){g2A.x,g2A.y},(v2){g2A.z,g2A.w},(v2){g2B.x,g2B.y},(v2){g2B.z,g2B.w}};
        v2 b2v[4] = {(v2){b2A.x,b2A.y},(v2){b2A.z,b2A.w},(v2){b2B.x,b2B.y},(v2){b2B.z,b2B.w}};
#pragma unroll
        for (int k = 0; k < 4; ++k) {
            G1S[k] = (S * 2.0f) * g1v[k];        // S*(2*g1)
            B1S[k] = S * (b1v[k] - g1v[k]);      // S*(b1-g1)
            G2c[k] = (ca * 2.0f) * g2v[k];       // ca*(2*g2)
            B2c[k] = ca * (b2v[k] - g2v[k]);     // ca*(b2-g2)
        }
    }

    // Gather this row's token; state is cxi = ca * xi.
    const int l   = g * GROUP_ + row;
    const int tok = gt[b * L_ + l];
    const float* xp = x + ((size_t)(b * L_ + tok)) * D_ + d0;

    v2 cxi[4], za[4];
    {
        float4 xA = *(const float4*)xp;
        float4 xB = *(const float4*)(xp + 4);
        const v2 cav = (v2){ca, ca};
        cxi[0] = cav * (v2){xA.x, xA.y}; cxi[1] = cav * (v2){xA.z, xA.w};
        cxi[2] = cav * (v2){xB.x, xB.y}; cxi[3] = cav * (v2){xB.z, xB.w};
    }
#pragma unroll
    for (int k = 0; k < 4; ++k) za[k] = (v2){0.0f, 0.0f};

    // Row 0 publishes its initial cxi into buffer 0
    if (row == 0) {
        float4 oA = {cxi[0].x, cxi[0].y, cxi[1].x, cxi[1].y};
        float4 oB = {cxi[2].x, cxi[2].y, cxi[3].x, cxi[3].y};
        *(float4*)&s_xj[0][d0]     = oA;
        *(float4*)&s_xj[0][d0 + 4] = oB;
    }
    __syncthreads();

    const v2 leak = (v2){0.01f, 0.01f};

    // Uniform split: each path pays exactly one v_pk_min / v_pk_max per elem.
    if (selMin) {
        STEP_LOOP(__builtin_elementwise_min)
    } else {
        STEP_LOOP(__builtin_elementwise_max)
    }

    // Recover xi = cxi / ca and xa = za / S.
    const float invS = 1.0f / S;
    const v2 invSv  = (v2){invS, invS};
    const v2 invCav = (v2){inv_ca, inv_ca};
    v2 xi[4], xa[4];
#pragma unroll
    for (int k = 0; k < 4; ++k) {
        xi[k] = cxi[k] * invCav;
        xa[k] = za[k] * invSv;
    }

    const bool valid = (g * GROUP_) < ctxlens[b];
    if (!valid) {
#pragma unroll
        for (int k = 0; k < 4; ++k) { xi[k] = (v2){0,0}; xa[k] = (v2){0,0}; }
    }

    // Scatter back through the permutation (bijective -> every out elem written)
    float* o1 = out + ((size_t)(b * L_ + tok)) * D_ + d0;
    float* o2 = o1 + (size_t)B_ * L_ * D_;
    float4 s1A = {xi[0].x, xi[0].y, xi[1].x, xi[1].y};
    float4 s1B = {xi[2].x, xi[2].y, xi[3].x, xi[3].y};
    float4 s2A = {xa[0].x, xa[0].y, xa[1].x, xa[1].y};
    float4 s2B = {xa[2].x, xa[2].y, xa[3].x, xa[3].y};
    *(float4*)o1       = s1A;
    *(float4*)(o1 + 4) = s1B;
    *(float4*)o2       = s2A;
    *(float4*)(o2 + 4) = s2B;
}

extern "C" void kernel_launch(void* const* d_in, const int* in_sizes, int n_in,
                              void* d_out, int out_size, void* d_ws, size_t ws_size,
                              hipStream_t stream) {
    const float* x  = (const float*)d_in[0];
    const int*   gt = (const int*)d_in[1];
    const int*   cl = (const int*)d_in[2];
    const float* W  = (const float*)d_in[3];
    const float* na = (const float*)d_in[4];
    const float* ng = (const float*)d_in[5];
    const float* nb = (const float*)d_in[6];
    float* out = (float*)d_out;

    ncn_kernel<<<B_ * NG_, 256, 0, stream>>>(x, gt, cl, W, na, ng, nb, out);
}